// Round 3
// baseline (4114.386 us; speedup 1.0000x reference)
//
#include <hip/hip_runtime.h>
#include <cstddef>

// MPNN layer, f32 (v3: edge_index as int32 per harness contract — int64 cast
// in v2 caused the memory-fault abort).
// Pipeline:
//   memset n_agg
//   K0: P = x @ W_msg[0:32], Q = x @ e_W1           (per-node precompute)
//   E1: msg = relu(P[s] + e@W_msg[32:64] + b) -> atomic scatter to n_agg[d]
//       h1_pre = Q[s]+Q[d] + (1+eps2)*(e@eW1) + eb1 -> block stats
//   F(e1) -> A1,C1 ; E2: recompute h1_pre, h1=relu(A1*h1p+C1), h2p=h1@eW2+b2 -> stats
//   F(e2) -> A2,C2 ; E3: recompute h2p, e_out = relu(A2*h2p+C2)
//   node path: same 3-stage structure on N=50k rows via h_n scratch (aliases P).

#define TPB 256

__device__ __forceinline__ void load_row(const float* __restrict__ p, float r[32]) {
    const float4* p4 = (const float4*)p;
#pragma unroll
    for (int q = 0; q < 8; ++q) {
        float4 v = p4[q];
        r[4*q+0] = v.x; r[4*q+1] = v.y; r[4*q+2] = v.z; r[4*q+3] = v.w;
    }
}

__device__ __forceinline__ void store_row(float* __restrict__ p, const float r[32]) {
    float4* p4 = (float4*)p;
#pragma unroll
    for (int q = 0; q < 8; ++q) {
        float4 v; v.x = r[4*q+0]; v.y = r[4*q+1]; v.z = r[4*q+2]; v.w = r[4*q+3];
        p4[q] = v;
    }
}

// acc[j] += sum_k a[k] * W[k*32+j]  (W row-major [32,32], uniform -> scalar loads)
__device__ __forceinline__ void matvec32(const float* __restrict__ W, const float a[32], float acc[32]) {
#pragma unroll
    for (int k = 0; k < 32; ++k) {
        float av = a[k];
#pragma unroll
        for (int j = 0; j < 32; ++j) acc[j] = fmaf(av, W[k*32 + j], acc[j]);
    }
}

// Column sums of h and h^2 over the block -> pb[blockIdx*64 + {0..31:sum, 32..63:sumsq}]
// LDS-transpose: write [256][33]-padded rows (bank = (t+j)%32, conflict-free),
// each thread column-sums a 32-row chunk (2-way conflicts = free on CDNA4),
// then fold the 8 chunk-partials.
__device__ __forceinline__ void stats_reduce(const float h[32], float* __restrict__ pb) {
    __shared__ float sh[256 * 33];
    const int t = threadIdx.x;
#pragma unroll
    for (int j = 0; j < 32; ++j) sh[t * 33 + j] = h[j];
    __syncthreads();
    const int c  = t & 31;
    const int r0 = (t >> 5) * 32;
    float s1 = 0.f, s2 = 0.f;
#pragma unroll
    for (int r = 0; r < 32; ++r) {
        float v = sh[(r0 + r) * 33 + c];
        s1 += v;
        s2 = fmaf(v, v, s2);
    }
    __syncthreads();          // before reusing sh
    sh[t] = s1; sh[256 + t] = s2;
    __syncthreads();
    if (t < 64) {
        const int col  = t & 31;
        const int half = t >> 5;            // 0: sum, 1: sumsq
        const float* base = sh + half * 256 + col;
        float acc = 0.f;
#pragma unroll
        for (int kk = 0; kk < 8; ++kk) acc += base[kk * 32];
        pb[(size_t)blockIdx.x * 64 + half * 32 + col] = acc;
    }
}

__global__ __launch_bounds__(TPB) void precompute_pq(
    const float* __restrict__ x, const float* __restrict__ Wmsg_top,
    const float* __restrict__ eW1, float* __restrict__ P, float* __restrict__ Q, int n)
{
    int i = blockIdx.x * TPB + threadIdx.x;
    if (i >= n) return;
    float xv[32]; load_row(x + (size_t)i * 32, xv);
    float acc[32];
#pragma unroll
    for (int j = 0; j < 32; ++j) acc[j] = 0.f;
    matvec32(Wmsg_top, xv, acc);
    store_row(P + (size_t)i * 32, acc);
#pragma unroll
    for (int j = 0; j < 32; ++j) acc[j] = 0.f;
    matvec32(eW1, xv, acc);
    store_row(Q + (size_t)i * 32, acc);
}

__global__ __launch_bounds__(TPB) void edge1_kernel(
    const float* __restrict__ e, const int* __restrict__ ei,
    const float* __restrict__ P, const float* __restrict__ Q,
    const float* __restrict__ Wmsg_lo, const float* __restrict__ b_msg,
    const float* __restrict__ e_b1, const float* __restrict__ eW1,
    const float* __restrict__ eps2p,
    float* __restrict__ n_agg, float* __restrict__ pb, int E)
{
    int eid = blockIdx.x * TPB + threadIdx.x;
    float h1[32];
    if (eid < E) {
        int s = ei[eid];                 // src
        int d = ei[(size_t)E + eid];     // dst
        float ev[32]; load_row(e + (size_t)eid * 32, ev);
        {   // message path: retire acc (and its atomics) before building h1
            float acc[32]; load_row(P + (size_t)s * 32, acc);
#pragma unroll
            for (int j = 0; j < 32; ++j) acc[j] += b_msg[j];
            matvec32(Wmsg_lo, ev, acc);
            float* na = n_agg + (size_t)d * 32;
#pragma unroll
            for (int j = 0; j < 32; ++j) unsafeAtomicAdd(&na[j], fmaxf(acc[j], 0.f));
        }
        load_row(Q + (size_t)s * 32, h1);
        {
            float qd[32]; load_row(Q + (size_t)d * 32, qd);
#pragma unroll
            for (int j = 0; j < 32; ++j) h1[j] += qd[j] + e_b1[j];
        }
        float t = 1.0f + eps2p[0];
#pragma unroll
        for (int k = 0; k < 32; ++k) ev[k] *= t;
        matvec32(eW1, ev, h1);
    } else {
#pragma unroll
        for (int j = 0; j < 32; ++j) h1[j] = 0.f;
    }
    stats_reduce(h1, pb);
}

__global__ __launch_bounds__(TPB) void edge2_kernel(
    const float* __restrict__ e, const int* __restrict__ ei,
    const float* __restrict__ Q, const float* __restrict__ e_b1,
    const float* __restrict__ eW1, const float* __restrict__ eps2p,
    const float* __restrict__ AC1,
    const float* __restrict__ eW2, const float* __restrict__ e_b2,
    float* __restrict__ pb, int E)
{
    int eid = blockIdx.x * TPB + threadIdx.x;
    float h2[32];
    if (eid < E) {
        int s = ei[eid];
        int d = ei[(size_t)E + eid];
        float ev[32]; load_row(e + (size_t)eid * 32, ev);
        float h1p[32];
        load_row(Q + (size_t)s * 32, h1p);
        {
            float qd[32]; load_row(Q + (size_t)d * 32, qd);
#pragma unroll
            for (int j = 0; j < 32; ++j) h1p[j] += qd[j] + e_b1[j];
        }
        float t = 1.0f + eps2p[0];
#pragma unroll
        for (int k = 0; k < 32; ++k) ev[k] *= t;
        matvec32(eW1, ev, h1p);
#pragma unroll
        for (int j = 0; j < 32; ++j) h1p[j] = fmaxf(fmaf(AC1[j], h1p[j], AC1[32 + j]), 0.f);
#pragma unroll
        for (int j = 0; j < 32; ++j) h2[j] = e_b2[j];
        matvec32(eW2, h1p, h2);
    } else {
#pragma unroll
        for (int j = 0; j < 32; ++j) h2[j] = 0.f;
    }
    stats_reduce(h2, pb);
}

__global__ __launch_bounds__(TPB) void edge3_kernel(
    const float* __restrict__ e, const int* __restrict__ ei,
    const float* __restrict__ Q, const float* __restrict__ e_b1,
    const float* __restrict__ eW1, const float* __restrict__ eps2p,
    const float* __restrict__ AC1,
    const float* __restrict__ eW2, const float* __restrict__ e_b2,
    const float* __restrict__ AC2,
    float* __restrict__ out_e, int E)
{
    int eid = blockIdx.x * TPB + threadIdx.x;
    if (eid >= E) return;
    int s = ei[eid];
    int d = ei[(size_t)E + eid];
    float ev[32]; load_row(e + (size_t)eid * 32, ev);
    float h1p[32];
    load_row(Q + (size_t)s * 32, h1p);
    {
        float qd[32]; load_row(Q + (size_t)d * 32, qd);
#pragma unroll
        for (int j = 0; j < 32; ++j) h1p[j] += qd[j] + e_b1[j];
    }
    float t = 1.0f + eps2p[0];
#pragma unroll
    for (int k = 0; k < 32; ++k) ev[k] *= t;
    matvec32(eW1, ev, h1p);
#pragma unroll
    for (int j = 0; j < 32; ++j) h1p[j] = fmaxf(fmaf(AC1[j], h1p[j], AC1[32 + j]), 0.f);
    float h2[32];
#pragma unroll
    for (int j = 0; j < 32; ++j) h2[j] = e_b2[j];
    matvec32(eW2, h1p, h2);
#pragma unroll
    for (int j = 0; j < 32; ++j) h2[j] = fmaxf(fmaf(AC2[j], h2[j], AC2[32 + j]), 0.f);
    store_row(out_e + (size_t)eid * 32, h2);
}

__global__ __launch_bounds__(TPB) void fin_kernel(
    const float* __restrict__ pb, int nblocks, double inv_count,
    const float* __restrict__ g, const float* __restrict__ be, float* __restrict__ AC)
{
    __shared__ double sh[256];
    const int c = threadIdx.x & 63;
    const int q = threadIdx.x >> 6;
    double acc = 0.0;
    for (int b = q; b < nblocks; b += 4) acc += (double)pb[(size_t)b * 64 + c];
    sh[threadIdx.x] = acc;
    __syncthreads();
    if (threadIdx.x < 64) {
        double t = sh[c] + sh[64 + c] + sh[128 + c] + sh[192 + c];
        sh[c] = t;
    }
    __syncthreads();
    if (threadIdx.x < 32) {
        int j = threadIdx.x;
        double mean = sh[j] * inv_count;
        double var  = sh[32 + j] * inv_count - mean * mean;
        float rstd = rsqrtf((float)var + 1e-5f);
        float gv = g[j];
        AC[j]      = gv * rstd;
        AC[32 + j] = be[j] - gv * (float)mean * rstd;
    }
}

__global__ __launch_bounds__(TPB) void node1_kernel(
    const float* __restrict__ x, const float* __restrict__ n_agg,
    const float* __restrict__ nW1, const float* __restrict__ n_b1,
    const float* __restrict__ eps1p, float* __restrict__ h_n,
    float* __restrict__ pb, int n)
{
    int i = blockIdx.x * TPB + threadIdx.x;
    float acc[32];
    if (i < n) {
        float u[32]; load_row(n_agg + (size_t)i * 32, u);
        float xv[32]; load_row(x + (size_t)i * 32, xv);
        float t = 1.0f + eps1p[0];
#pragma unroll
        for (int j = 0; j < 32; ++j) u[j] = fmaf(t, xv[j], u[j]);
#pragma unroll
        for (int j = 0; j < 32; ++j) acc[j] = n_b1[j];
        matvec32(nW1, u, acc);
        store_row(h_n + (size_t)i * 32, acc);
    } else {
#pragma unroll
        for (int j = 0; j < 32; ++j) acc[j] = 0.f;
    }
    stats_reduce(acc, pb);
}

__global__ __launch_bounds__(TPB) void node2_kernel(
    const float* __restrict__ AC1, const float* __restrict__ nW2,
    const float* __restrict__ n_b2, float* __restrict__ h_n,
    float* __restrict__ pb, int n)
{
    int i = blockIdx.x * TPB + threadIdx.x;
    float acc[32];
    if (i < n) {
        float hp[32]; load_row(h_n + (size_t)i * 32, hp);
#pragma unroll
        for (int j = 0; j < 32; ++j) hp[j] = fmaxf(fmaf(AC1[j], hp[j], AC1[32 + j]), 0.f);
#pragma unroll
        for (int j = 0; j < 32; ++j) acc[j] = n_b2[j];
        matvec32(nW2, hp, acc);
        store_row(h_n + (size_t)i * 32, acc);
    } else {
#pragma unroll
        for (int j = 0; j < 32; ++j) acc[j] = 0.f;
    }
    stats_reduce(acc, pb);
}

__global__ __launch_bounds__(TPB) void node3_kernel(
    const float* __restrict__ AC2, const float* __restrict__ h_n,
    float* __restrict__ out_n, int n)
{
    int i = blockIdx.x * TPB + threadIdx.x;
    if (i >= n) return;
    float hp[32]; load_row(h_n + (size_t)i * 32, hp);
    float o[32];
#pragma unroll
    for (int j = 0; j < 32; ++j) o[j] = fmaxf(fmaf(AC2[j], hp[j], AC2[32 + j]), 0.f);
    store_row(out_n + (size_t)i * 32, o);
}

extern "C" void kernel_launch(void* const* d_in, const int* in_sizes, int n_in,
                              void* d_out, int out_size, void* d_ws, size_t ws_size,
                              hipStream_t stream) {
    const float* x        = (const float*)d_in[0];
    const float* e        = (const float*)d_in[1];
    const int*   ei       = (const int*)d_in[2];     // int32 per harness contract
    const float* W_msg    = (const float*)d_in[3];
    const float* b_msg    = (const float*)d_in[4];
    const float* n_W1     = (const float*)d_in[5];
    const float* n_b1     = (const float*)d_in[6];
    const float* n_g1     = (const float*)d_in[7];
    const float* n_be1    = (const float*)d_in[8];
    const float* n_W2     = (const float*)d_in[9];
    const float* n_b2     = (const float*)d_in[10];
    const float* n_g2     = (const float*)d_in[11];
    const float* n_be2    = (const float*)d_in[12];
    const float* e_W1     = (const float*)d_in[13];
    const float* e_b1     = (const float*)d_in[14];
    const float* e_g1     = (const float*)d_in[15];
    const float* e_be1    = (const float*)d_in[16];
    const float* e_W2     = (const float*)d_in[17];
    const float* e_b2     = (const float*)d_in[18];
    const float* e_g2     = (const float*)d_in[19];
    const float* e_be2    = (const float*)d_in[20];
    const float* eps1     = (const float*)d_in[21];
    const float* eps2     = (const float*)d_in[22];

    const int N = in_sizes[0] / 32;   // 50000
    const int E = in_sizes[1] / 32;   // 1600000
    const int NB = (N + TPB - 1) / TPB;
    const int EB = (E + TPB - 1) / TPB;

    char* ws = (char*)d_ws;
    const size_t nb = (size_t)N * 32 * sizeof(float);
    float* n_agg = (float*)(ws);
    float* P     = (float*)(ws + nb);        // dead after edge1
    float* Q     = (float*)(ws + 2 * nb);
    float* h_n   = P;                         // node scratch aliases P (safe: stream-ordered)
    float* pb    = (float*)(ws + 3 * nb);
    float* AC    = (float*)(ws + 3 * nb + (size_t)EB * 64 * sizeof(float));
    // AC layout: [0:64) e-layer1, [64:128) e-layer2, [128:192) n-layer1, [192:256) n-layer2

    float* out_n = (float*)d_out;
    float* out_e = (float*)d_out + (size_t)N * 32;

    hipMemsetAsync(n_agg, 0, nb, stream);

    precompute_pq<<<NB, TPB, 0, stream>>>(x, W_msg /*rows 0..31*/, e_W1, P, Q, N);

    edge1_kernel<<<EB, TPB, 0, stream>>>(e, ei, P, Q, W_msg + 32 * 32, b_msg,
                                         e_b1, e_W1, eps2, n_agg, pb, E);
    fin_kernel<<<1, TPB, 0, stream>>>(pb, EB, 1.0 / (double)E, e_g1, e_be1, AC + 0);

    edge2_kernel<<<EB, TPB, 0, stream>>>(e, ei, Q, e_b1, e_W1, eps2, AC + 0,
                                         e_W2, e_b2, pb, E);
    fin_kernel<<<1, TPB, 0, stream>>>(pb, EB, 1.0 / (double)E, e_g2, e_be2, AC + 64);

    edge3_kernel<<<EB, TPB, 0, stream>>>(e, ei, Q, e_b1, e_W1, eps2, AC + 0,
                                         e_W2, e_b2, AC + 64, out_e, E);

    node1_kernel<<<NB, TPB, 0, stream>>>(x, n_agg, n_W1, n_b1, eps1, h_n, pb, N);
    fin_kernel<<<1, TPB, 0, stream>>>(pb, NB, 1.0 / (double)N, n_g1, n_be1, AC + 128);
    node2_kernel<<<NB, TPB, 0, stream>>>(AC + 128, n_W2, n_b2, h_n, pb, N);
    fin_kernel<<<1, TPB, 0, stream>>>(pb, NB, 1.0 / (double)N, n_g2, n_be2, AC + 192);
    node3_kernel<<<NB, TPB, 0, stream>>>(AC + 192, h_n, out_n, N);
}

// Round 5
// 2077.636 us; speedup vs baseline: 1.9803x; 1.9803x over previous
//
#include <hip/hip_runtime.h>
#include <cstddef>

// MPNN layer, f32 (v4 resubmit: atomic-free aggregation via per-call CSR + pull-gather).
// v3 post-mortem: 51.2M f32 scatter atomics = 1.6GB of 32B fabric RMWs = 2.7ms.
// Pipeline:
//   memset count
//   K0: P = x @ W_msg[0:32] + b_msg, Q = x @ e_W1
//   hist -> scanA/B/C -> scatter  (CSR: row_start/count/perm, int atomics only)
//   E1: h1_pre = Q[s]+Q[d] + (1+eps2)*(e@eW1) + eb1 -> stats   (no messages!)
//   F(e1); E2: recompute h1p, h1=relu(A1*h1p+C1), h2p=h1@eW2+b2 -> stats
//   F(e2); E3: recompute, e_out = relu(A2*h2p+C2)
//   G: per-node pull: agg = sum relu(P[s]+e@W_lo) over incoming edges;
//      fused node layer1 -> h_n (aliases Q), stats
//   F(n1); node2 -> stats; F(n2); node3 -> out_n

#define TPB 256

__device__ __forceinline__ void load_row(const float* __restrict__ p, float r[32]) {
    const float4* p4 = (const float4*)p;
#pragma unroll
    for (int q = 0; q < 8; ++q) {
        float4 v = p4[q];
        r[4*q+0] = v.x; r[4*q+1] = v.y; r[4*q+2] = v.z; r[4*q+3] = v.w;
    }
}

__device__ __forceinline__ void store_row(float* __restrict__ p, const float r[32]) {
    float4* p4 = (float4*)p;
#pragma unroll
    for (int q = 0; q < 8; ++q) {
        float4 v; v.x = r[4*q+0]; v.y = r[4*q+1]; v.z = r[4*q+2]; v.w = r[4*q+3];
        p4[q] = v;
    }
}

// acc[j] += sum_k a[k] * W[k*32+j]  (W row-major [32,32], uniform -> scalar loads)
__device__ __forceinline__ void matvec32(const float* __restrict__ W, const float a[32], float acc[32]) {
#pragma unroll
    for (int k = 0; k < 32; ++k) {
        float av = a[k];
#pragma unroll
        for (int j = 0; j < 32; ++j) acc[j] = fmaf(av, W[k*32 + j], acc[j]);
    }
}

// Column sums of h and h^2 over the block -> pb[blockIdx*64 + {0..31:sum, 32..63:sumsq}]
__device__ __forceinline__ void stats_reduce(const float h[32], float* __restrict__ pb) {
    __shared__ float sh[256 * 33];
    const int t = threadIdx.x;
#pragma unroll
    for (int j = 0; j < 32; ++j) sh[t * 33 + j] = h[j];
    __syncthreads();
    const int c  = t & 31;
    const int r0 = (t >> 5) * 32;
    float s1 = 0.f, s2 = 0.f;
#pragma unroll
    for (int r = 0; r < 32; ++r) {
        float v = sh[(r0 + r) * 33 + c];
        s1 += v;
        s2 = fmaf(v, v, s2);
    }
    __syncthreads();
    sh[t] = s1; sh[256 + t] = s2;
    __syncthreads();
    if (t < 64) {
        const int col  = t & 31;
        const int half = t >> 5;
        const float* base = sh + half * 256 + col;
        float acc = 0.f;
#pragma unroll
        for (int kk = 0; kk < 8; ++kk) acc += base[kk * 32];
        pb[(size_t)blockIdx.x * 64 + half * 32 + col] = acc;
    }
}

__global__ __launch_bounds__(TPB) void precompute_pq(
    const float* __restrict__ x, const float* __restrict__ Wmsg_top,
    const float* __restrict__ b_msg, const float* __restrict__ eW1,
    float* __restrict__ P, float* __restrict__ Q, int n)
{
    int i = blockIdx.x * TPB + threadIdx.x;
    if (i >= n) return;
    float xv[32]; load_row(x + (size_t)i * 32, xv);
    float acc[32];
#pragma unroll
    for (int j = 0; j < 32; ++j) acc[j] = b_msg[j];   // fold bias into P
    matvec32(Wmsg_top, xv, acc);
    store_row(P + (size_t)i * 32, acc);
#pragma unroll
    for (int j = 0; j < 32; ++j) acc[j] = 0.f;
    matvec32(eW1, xv, acc);
    store_row(Q + (size_t)i * 32, acc);
}

// ---------- CSR build ----------
__global__ __launch_bounds__(TPB) void hist_kernel(
    const int* __restrict__ ei, int* __restrict__ count, int E)
{
    int eid = blockIdx.x * TPB + threadIdx.x;
    if (eid < E) atomicAdd(&count[ei[(size_t)E + eid]], 1);
}

__global__ __launch_bounds__(TPB) void scanA_kernel(
    const int* __restrict__ count, int* __restrict__ row_start,
    int* __restrict__ tops, int n)
{
    __shared__ int s[TPB];
    int i = blockIdx.x * TPB + threadIdx.x;
    int v = (i < n) ? count[i] : 0;
    s[threadIdx.x] = v;
    __syncthreads();
#pragma unroll
    for (int off = 1; off < TPB; off <<= 1) {
        int u = (threadIdx.x >= off) ? s[threadIdx.x - off] : 0;
        __syncthreads();
        s[threadIdx.x] += u;
        __syncthreads();
    }
    if (i < n) row_start[i] = s[threadIdx.x] - v;          // exclusive within chunk
    if (threadIdx.x == TPB - 1) tops[blockIdx.x] = s[TPB - 1];
}

__global__ __launch_bounds__(TPB) void scanB_kernel(int* __restrict__ tops, int nb)
{
    __shared__ int s[TPB];
    int carry = 0;
    for (int base = 0; base < nb; base += TPB) {
        int i = base + threadIdx.x;
        int v = (i < nb) ? tops[i] : 0;
        __syncthreads();
        s[threadIdx.x] = v;
        __syncthreads();
#pragma unroll
        for (int off = 1; off < TPB; off <<= 1) {
            int u = (threadIdx.x >= off) ? s[threadIdx.x - off] : 0;
            __syncthreads();
            s[threadIdx.x] += u;
            __syncthreads();
        }
        if (i < nb) tops[i] = carry + s[threadIdx.x] - v;  // exclusive global
        carry += s[TPB - 1];
    }
}

__global__ __launch_bounds__(TPB) void scanC_kernel(
    int* __restrict__ row_start, const int* __restrict__ tops,
    int* __restrict__ woff, int n)
{
    int i = blockIdx.x * TPB + threadIdx.x;
    if (i < n) {
        int v = row_start[i] + tops[blockIdx.x];
        row_start[i] = v;
        woff[i] = v;
    }
}

__global__ __launch_bounds__(TPB) void scatter_kernel(
    const int* __restrict__ ei, int* __restrict__ woff, int* __restrict__ perm, int E)
{
    int eid = blockIdx.x * TPB + threadIdx.x;
    if (eid < E) {
        int d = ei[(size_t)E + eid];
        int pos = atomicAdd(&woff[d], 1);
        perm[pos] = eid;
    }
}

// ---------- edge pipeline (stats / recompute) ----------
__global__ __launch_bounds__(TPB) void edge1_stats(
    const float* __restrict__ e, const int* __restrict__ ei,
    const float* __restrict__ Q, const float* __restrict__ e_b1,
    const float* __restrict__ eW1, const float* __restrict__ eps2p,
    float* __restrict__ pb, int E)
{
    int eid = blockIdx.x * TPB + threadIdx.x;
    float h1[32];
    if (eid < E) {
        int s = ei[eid];
        int d = ei[(size_t)E + eid];
        float ev[32]; load_row(e + (size_t)eid * 32, ev);
        load_row(Q + (size_t)s * 32, h1);
        {
            float qd[32]; load_row(Q + (size_t)d * 32, qd);
#pragma unroll
            for (int j = 0; j < 32; ++j) h1[j] += qd[j] + e_b1[j];
        }
        float t = 1.0f + eps2p[0];
#pragma unroll
        for (int k = 0; k < 32; ++k) ev[k] *= t;
        matvec32(eW1, ev, h1);
    } else {
#pragma unroll
        for (int j = 0; j < 32; ++j) h1[j] = 0.f;
    }
    stats_reduce(h1, pb);
}

__global__ __launch_bounds__(TPB) void edge2_kernel(
    const float* __restrict__ e, const int* __restrict__ ei,
    const float* __restrict__ Q, const float* __restrict__ e_b1,
    const float* __restrict__ eW1, const float* __restrict__ eps2p,
    const float* __restrict__ AC1,
    const float* __restrict__ eW2, const float* __restrict__ e_b2,
    float* __restrict__ pb, int E)
{
    int eid = blockIdx.x * TPB + threadIdx.x;
    float h2[32];
    if (eid < E) {
        int s = ei[eid];
        int d = ei[(size_t)E + eid];
        float ev[32]; load_row(e + (size_t)eid * 32, ev);
        float h1p[32];
        load_row(Q + (size_t)s * 32, h1p);
        {
            float qd[32]; load_row(Q + (size_t)d * 32, qd);
#pragma unroll
            for (int j = 0; j < 32; ++j) h1p[j] += qd[j] + e_b1[j];
        }
        float t = 1.0f + eps2p[0];
#pragma unroll
        for (int k = 0; k < 32; ++k) ev[k] *= t;
        matvec32(eW1, ev, h1p);
#pragma unroll
        for (int j = 0; j < 32; ++j) h1p[j] = fmaxf(fmaf(AC1[j], h1p[j], AC1[32 + j]), 0.f);
#pragma unroll
        for (int j = 0; j < 32; ++j) h2[j] = e_b2[j];
        matvec32(eW2, h1p, h2);
    } else {
#pragma unroll
        for (int j = 0; j < 32; ++j) h2[j] = 0.f;
    }
    stats_reduce(h2, pb);
}

__global__ __launch_bounds__(TPB) void edge3_kernel(
    const float* __restrict__ e, const int* __restrict__ ei,
    const float* __restrict__ Q, const float* __restrict__ e_b1,
    const float* __restrict__ eW1, const float* __restrict__ eps2p,
    const float* __restrict__ AC1,
    const float* __restrict__ eW2, const float* __restrict__ e_b2,
    const float* __restrict__ AC2,
    float* __restrict__ out_e, int E)
{
    int eid = blockIdx.x * TPB + threadIdx.x;
    if (eid >= E) return;
    int s = ei[eid];
    int d = ei[(size_t)E + eid];
    float ev[32]; load_row(e + (size_t)eid * 32, ev);
    float h1p[32];
    load_row(Q + (size_t)s * 32, h1p);
    {
        float qd[32]; load_row(Q + (size_t)d * 32, qd);
#pragma unroll
        for (int j = 0; j < 32; ++j) h1p[j] += qd[j] + e_b1[j];
    }
    float t = 1.0f + eps2p[0];
#pragma unroll
    for (int k = 0; k < 32; ++k) ev[k] *= t;
    matvec32(eW1, ev, h1p);
#pragma unroll
    for (int j = 0; j < 32; ++j) h1p[j] = fmaxf(fmaf(AC1[j], h1p[j], AC1[32 + j]), 0.f);
    float h2[32];
#pragma unroll
    for (int j = 0; j < 32; ++j) h2[j] = e_b2[j];
    matvec32(eW2, h1p, h2);
#pragma unroll
    for (int j = 0; j < 32; ++j) h2[j] = fmaxf(fmaf(AC2[j], h2[j], AC2[32 + j]), 0.f);
    store_row(out_e + (size_t)eid * 32, h2);
}

__global__ __launch_bounds__(TPB) void fin_kernel(
    const float* __restrict__ pb, int nblocks, double inv_count,
    const float* __restrict__ g, const float* __restrict__ be, float* __restrict__ AC)
{
    __shared__ double sh[256];
    const int c = threadIdx.x & 63;
    const int q = threadIdx.x >> 6;
    double acc = 0.0;
    for (int b = q; b < nblocks; b += 4) acc += (double)pb[(size_t)b * 64 + c];
    sh[threadIdx.x] = acc;
    __syncthreads();
    if (threadIdx.x < 64) {
        double t = sh[c] + sh[64 + c] + sh[128 + c] + sh[192 + c];
        sh[c] = t;
    }
    __syncthreads();
    if (threadIdx.x < 32) {
        int j = threadIdx.x;
        double mean = sh[j] * inv_count;
        double var  = sh[32 + j] * inv_count - mean * mean;
        float rstd = rsqrtf((float)var + 1e-5f);
        float gv = g[j];
        AC[j]      = gv * rstd;
        AC[32 + j] = be[j] - gv * (float)mean * rstd;
    }
}

// ---------- node path: pull-gather + fused layer1 ----------
__global__ __launch_bounds__(TPB) void gather_node1(
    const float* __restrict__ x, const float* __restrict__ e,
    const int* __restrict__ ei, const float* __restrict__ P,
    const float* __restrict__ Wmsg_lo,
    const int* __restrict__ row_start, const int* __restrict__ count,
    const int* __restrict__ perm,
    const float* __restrict__ eps1p,
    const float* __restrict__ nW1, const float* __restrict__ n_b1,
    float* __restrict__ h_n, float* __restrict__ pb, int n)
{
    int i = blockIdx.x * TPB + threadIdx.x;
    float h[32];
    if (i < n) {
        float acc[32];
#pragma unroll
        for (int j = 0; j < 32; ++j) acc[j] = 0.f;
        int start = row_start[i];
        int deg   = count[i];
        for (int k = 0; k < deg; ++k) {
            int eid = perm[start + k];
            int s   = ei[eid];
            float ev[32]; load_row(e + (size_t)eid * 32, ev);
            float m[32];  load_row(P + (size_t)s * 32, m);   // P has b_msg folded in
            matvec32(Wmsg_lo, ev, m);
#pragma unroll
            for (int j = 0; j < 32; ++j) acc[j] += fmaxf(m[j], 0.f);
        }
        float xv[32]; load_row(x + (size_t)i * 32, xv);
        float t = 1.0f + eps1p[0];
#pragma unroll
        for (int j = 0; j < 32; ++j) acc[j] = fmaf(t, xv[j], acc[j]);
#pragma unroll
        for (int j = 0; j < 32; ++j) h[j] = n_b1[j];
        matvec32(nW1, acc, h);
        store_row(h_n + (size_t)i * 32, h);
    } else {
#pragma unroll
        for (int j = 0; j < 32; ++j) h[j] = 0.f;
    }
    stats_reduce(h, pb);
}

__global__ __launch_bounds__(TPB) void node2_kernel(
    const float* __restrict__ AC1, const float* __restrict__ nW2,
    const float* __restrict__ n_b2, float* __restrict__ h_n,
    float* __restrict__ pb, int n)
{
    int i = blockIdx.x * TPB + threadIdx.x;
    float acc[32];
    if (i < n) {
        float hp[32]; load_row(h_n + (size_t)i * 32, hp);
#pragma unroll
        for (int j = 0; j < 32; ++j) hp[j] = fmaxf(fmaf(AC1[j], hp[j], AC1[32 + j]), 0.f);
#pragma unroll
        for (int j = 0; j < 32; ++j) acc[j] = n_b2[j];
        matvec32(nW2, hp, acc);
        store_row(h_n + (size_t)i * 32, acc);
    } else {
#pragma unroll
        for (int j = 0; j < 32; ++j) acc[j] = 0.f;
    }
    stats_reduce(acc, pb);
}

__global__ __launch_bounds__(TPB) void node3_kernel(
    const float* __restrict__ AC2, const float* __restrict__ h_n,
    float* __restrict__ out_n, int n)
{
    int i = blockIdx.x * TPB + threadIdx.x;
    if (i >= n) return;
    float hp[32]; load_row(h_n + (size_t)i * 32, hp);
    float o[32];
#pragma unroll
    for (int j = 0; j < 32; ++j) o[j] = fmaxf(fmaf(AC2[j], hp[j], AC2[32 + j]), 0.f);
    store_row(out_n + (size_t)i * 32, o);
}

extern "C" void kernel_launch(void* const* d_in, const int* in_sizes, int n_in,
                              void* d_out, int out_size, void* d_ws, size_t ws_size,
                              hipStream_t stream) {
    const float* x        = (const float*)d_in[0];
    const float* e        = (const float*)d_in[1];
    const int*   ei       = (const int*)d_in[2];
    const float* W_msg    = (const float*)d_in[3];
    const float* b_msg    = (const float*)d_in[4];
    const float* n_W1     = (const float*)d_in[5];
    const float* n_b1     = (const float*)d_in[6];
    const float* n_g1     = (const float*)d_in[7];
    const float* n_be1    = (const float*)d_in[8];
    const float* n_W2     = (const float*)d_in[9];
    const float* n_b2     = (const float*)d_in[10];
    const float* n_g2     = (const float*)d_in[11];
    const float* n_be2    = (const float*)d_in[12];
    const float* e_W1     = (const float*)d_in[13];
    const float* e_b1     = (const float*)d_in[14];
    const float* e_g1     = (const float*)d_in[15];
    const float* e_be1    = (const float*)d_in[16];
    const float* e_W2     = (const float*)d_in[17];
    const float* e_b2     = (const float*)d_in[18];
    const float* e_g2     = (const float*)d_in[19];
    const float* e_be2    = (const float*)d_in[20];
    const float* eps1     = (const float*)d_in[21];
    const float* eps2     = (const float*)d_in[22];

    const int N = in_sizes[0] / 32;   // 50000
    const int E = in_sizes[1] / 32;   // 1600000
    const int NB = (N + TPB - 1) / TPB;   // 196
    const int EB = (E + TPB - 1) / TPB;   // 6250

    char* ws = (char*)d_ws;
    const size_t nb = (size_t)N * 32 * sizeof(float);       // 6.4 MB
    float* P         = (float*)(ws);
    float* Q         = (float*)(ws + nb);
    float* h_n       = Q;                                    // Q dead after edge3
    float* pb        = (float*)(ws + 2 * nb);
    size_t pb_bytes  = (size_t)EB * 64 * sizeof(float);      // 1.6 MB
    int*   perm      = (int*)(ws + 2 * nb + pb_bytes);
    int*   count     = (int*)(ws + 2 * nb + pb_bytes + (size_t)E * sizeof(int));
    int*   row_start = count + N;
    int*   woff      = row_start + N;
    int*   tops      = woff + N;                             // NB ints
    float* AC        = (float*)(tops + ((NB + 255) & ~255)); // aligned past tops
    // AC layout: [0:64) e-L1, [64:128) e-L2, [128:192) n-L1, [192:256) n-L2

    float* out_n = (float*)d_out;
    float* out_e = (float*)d_out + (size_t)N * 32;

    hipMemsetAsync(count, 0, (size_t)N * sizeof(int), stream);

    precompute_pq<<<NB, TPB, 0, stream>>>(x, W_msg, b_msg, e_W1, P, Q, N);

    // CSR build (int atomics only)
    hist_kernel   <<<EB, TPB, 0, stream>>>(ei, count, E);
    scanA_kernel  <<<NB, TPB, 0, stream>>>(count, row_start, tops, N);
    scanB_kernel  <<<1,  TPB, 0, stream>>>(tops, NB);
    scanC_kernel  <<<NB, TPB, 0, stream>>>(row_start, tops, woff, N);
    scatter_kernel<<<EB, TPB, 0, stream>>>(ei, woff, perm, E);

    // edge pipeline
    edge1_stats<<<EB, TPB, 0, stream>>>(e, ei, Q, e_b1, e_W1, eps2, pb, E);
    fin_kernel<<<1, TPB, 0, stream>>>(pb, EB, 1.0 / (double)E, e_g1, e_be1, AC + 0);
    edge2_kernel<<<EB, TPB, 0, stream>>>(e, ei, Q, e_b1, e_W1, eps2, AC + 0,
                                         e_W2, e_b2, pb, E);
    fin_kernel<<<1, TPB, 0, stream>>>(pb, EB, 1.0 / (double)E, e_g2, e_be2, AC + 64);
    edge3_kernel<<<EB, TPB, 0, stream>>>(e, ei, Q, e_b1, e_W1, eps2, AC + 0,
                                         e_W2, e_b2, AC + 64, out_e, E);

    // node pipeline (gather must follow edge3: h_n aliases Q)
    gather_node1<<<NB, TPB, 0, stream>>>(x, e, ei, P, W_msg + 32 * 32,
                                         row_start, count, perm, eps1,
                                         n_W1, n_b1, h_n, pb, N);
    fin_kernel<<<1, TPB, 0, stream>>>(pb, NB, 1.0 / (double)N, n_g1, n_be1, AC + 128);
    node2_kernel<<<NB, TPB, 0, stream>>>(AC + 128, n_W2, n_b2, h_n, pb, N);
    fin_kernel<<<1, TPB, 0, stream>>>(pb, NB, 1.0 / (double)N, n_g2, n_be2, AC + 192);
    node3_kernel<<<NB, TPB, 0, stream>>>(AC + 192, h_n, out_n, N);
}

// Round 6
// 1313.990 us; speedup vs baseline: 3.1312x; 1.5812x over previous
//
#include <hip/hip_runtime.h>
#include <cstddef>

// MPNN layer, f32 (v5: hierarchical BN-stats reduction).
// v4 post-mortem: single-workgroup fin_kernel on 6250-row pb = 423us each
// (1.9 GB/s latency-bound single CU) -- 846us of 2078us total.
// Fix: mid_reduce (64 blocks, double-acc) -> fin reads 64 rows.

#define TPB 256

__device__ __forceinline__ void load_row(const float* __restrict__ p, float r[32]) {
    const float4* p4 = (const float4*)p;
#pragma unroll
    for (int q = 0; q < 8; ++q) {
        float4 v = p4[q];
        r[4*q+0] = v.x; r[4*q+1] = v.y; r[4*q+2] = v.z; r[4*q+3] = v.w;
    }
}

__device__ __forceinline__ void store_row(float* __restrict__ p, const float r[32]) {
    float4* p4 = (float4*)p;
#pragma unroll
    for (int q = 0; q < 8; ++q) {
        float4 v; v.x = r[4*q+0]; v.y = r[4*q+1]; v.z = r[4*q+2]; v.w = r[4*q+3];
        p4[q] = v;
    }
}

// acc[j] += sum_k a[k] * W[k*32+j]  (W row-major [32,32], uniform -> scalar loads)
__device__ __forceinline__ void matvec32(const float* __restrict__ W, const float a[32], float acc[32]) {
#pragma unroll
    for (int k = 0; k < 32; ++k) {
        float av = a[k];
#pragma unroll
        for (int j = 0; j < 32; ++j) acc[j] = fmaf(av, W[k*32 + j], acc[j]);
    }
}

// Column sums of h and h^2 over the block -> pb[blockIdx*64 + {0..31:sum, 32..63:sumsq}]
__device__ __forceinline__ void stats_reduce(const float h[32], float* __restrict__ pb) {
    __shared__ float sh[256 * 33];
    const int t = threadIdx.x;
#pragma unroll
    for (int j = 0; j < 32; ++j) sh[t * 33 + j] = h[j];
    __syncthreads();
    const int c  = t & 31;
    const int r0 = (t >> 5) * 32;
    float s1 = 0.f, s2 = 0.f;
#pragma unroll
    for (int r = 0; r < 32; ++r) {
        float v = sh[(r0 + r) * 33 + c];
        s1 += v;
        s2 = fmaf(v, v, s2);
    }
    __syncthreads();
    sh[t] = s1; sh[256 + t] = s2;
    __syncthreads();
    if (t < 64) {
        const int col  = t & 31;
        const int half = t >> 5;
        const float* base = sh + half * 256 + col;
        float acc = 0.f;
#pragma unroll
        for (int kk = 0; kk < 8; ++kk) acc += base[kk * 32];
        pb[(size_t)blockIdx.x * 64 + half * 32 + col] = acc;
    }
}

__global__ __launch_bounds__(TPB) void precompute_pq(
    const float* __restrict__ x, const float* __restrict__ Wmsg_top,
    const float* __restrict__ b_msg, const float* __restrict__ eW1,
    float* __restrict__ P, float* __restrict__ Q, int n)
{
    int i = blockIdx.x * TPB + threadIdx.x;
    if (i >= n) return;
    float xv[32]; load_row(x + (size_t)i * 32, xv);
    float acc[32];
#pragma unroll
    for (int j = 0; j < 32; ++j) acc[j] = b_msg[j];   // fold bias into P
    matvec32(Wmsg_top, xv, acc);
    store_row(P + (size_t)i * 32, acc);
#pragma unroll
    for (int j = 0; j < 32; ++j) acc[j] = 0.f;
    matvec32(eW1, xv, acc);
    store_row(Q + (size_t)i * 32, acc);
}

// ---------- CSR build ----------
__global__ __launch_bounds__(TPB) void hist_kernel(
    const int* __restrict__ ei, int* __restrict__ count, int E)
{
    int eid = blockIdx.x * TPB + threadIdx.x;
    if (eid < E) atomicAdd(&count[ei[(size_t)E + eid]], 1);
}

__global__ __launch_bounds__(TPB) void scanA_kernel(
    const int* __restrict__ count, int* __restrict__ row_start,
    int* __restrict__ tops, int n)
{
    __shared__ int s[TPB];
    int i = blockIdx.x * TPB + threadIdx.x;
    int v = (i < n) ? count[i] : 0;
    s[threadIdx.x] = v;
    __syncthreads();
#pragma unroll
    for (int off = 1; off < TPB; off <<= 1) {
        int u = (threadIdx.x >= off) ? s[threadIdx.x - off] : 0;
        __syncthreads();
        s[threadIdx.x] += u;
        __syncthreads();
    }
    if (i < n) row_start[i] = s[threadIdx.x] - v;          // exclusive within chunk
    if (threadIdx.x == TPB - 1) tops[blockIdx.x] = s[TPB - 1];
}

__global__ __launch_bounds__(TPB) void scanB_kernel(int* __restrict__ tops, int nb)
{
    __shared__ int s[TPB];
    int carry = 0;
    for (int base = 0; base < nb; base += TPB) {
        int i = base + threadIdx.x;
        int v = (i < nb) ? tops[i] : 0;
        __syncthreads();
        s[threadIdx.x] = v;
        __syncthreads();
#pragma unroll
        for (int off = 1; off < TPB; off <<= 1) {
            int u = (threadIdx.x >= off) ? s[threadIdx.x - off] : 0;
            __syncthreads();
            s[threadIdx.x] += u;
            __syncthreads();
        }
        if (i < nb) tops[i] = carry + s[threadIdx.x] - v;  // exclusive global
        carry += s[TPB - 1];
    }
}

__global__ __launch_bounds__(TPB) void scanC_kernel(
    int* __restrict__ row_start, const int* __restrict__ tops,
    int* __restrict__ woff, int n)
{
    int i = blockIdx.x * TPB + threadIdx.x;
    if (i < n) {
        int v = row_start[i] + tops[blockIdx.x];
        row_start[i] = v;
        woff[i] = v;
    }
}

__global__ __launch_bounds__(TPB) void scatter_kernel(
    const int* __restrict__ ei, int* __restrict__ woff, int* __restrict__ perm, int E)
{
    int eid = blockIdx.x * TPB + threadIdx.x;
    if (eid < E) {
        int d = ei[(size_t)E + eid];
        int pos = atomicAdd(&woff[d], 1);
        perm[pos] = eid;
    }
}

// ---------- edge pipeline (stats / recompute) ----------
__global__ __launch_bounds__(TPB) void edge1_stats(
    const float* __restrict__ e, const int* __restrict__ ei,
    const float* __restrict__ Q, const float* __restrict__ e_b1,
    const float* __restrict__ eW1, const float* __restrict__ eps2p,
    float* __restrict__ pb, int E)
{
    int eid = blockIdx.x * TPB + threadIdx.x;
    float h1[32];
    if (eid < E) {
        int s = ei[eid];
        int d = ei[(size_t)E + eid];
        float ev[32]; load_row(e + (size_t)eid * 32, ev);
        load_row(Q + (size_t)s * 32, h1);
        {
            float qd[32]; load_row(Q + (size_t)d * 32, qd);
#pragma unroll
            for (int j = 0; j < 32; ++j) h1[j] += qd[j] + e_b1[j];
        }
        float t = 1.0f + eps2p[0];
#pragma unroll
        for (int k = 0; k < 32; ++k) ev[k] *= t;
        matvec32(eW1, ev, h1);
    } else {
#pragma unroll
        for (int j = 0; j < 32; ++j) h1[j] = 0.f;
    }
    stats_reduce(h1, pb);
}

__global__ __launch_bounds__(TPB) void edge2_kernel(
    const float* __restrict__ e, const int* __restrict__ ei,
    const float* __restrict__ Q, const float* __restrict__ e_b1,
    const float* __restrict__ eW1, const float* __restrict__ eps2p,
    const float* __restrict__ AC1,
    const float* __restrict__ eW2, const float* __restrict__ e_b2,
    float* __restrict__ pb, int E)
{
    int eid = blockIdx.x * TPB + threadIdx.x;
    float h2[32];
    if (eid < E) {
        int s = ei[eid];
        int d = ei[(size_t)E + eid];
        float ev[32]; load_row(e + (size_t)eid * 32, ev);
        float h1p[32];
        load_row(Q + (size_t)s * 32, h1p);
        {
            float qd[32]; load_row(Q + (size_t)d * 32, qd);
#pragma unroll
            for (int j = 0; j < 32; ++j) h1p[j] += qd[j] + e_b1[j];
        }
        float t = 1.0f + eps2p[0];
#pragma unroll
        for (int k = 0; k < 32; ++k) ev[k] *= t;
        matvec32(eW1, ev, h1p);
#pragma unroll
        for (int j = 0; j < 32; ++j) h1p[j] = fmaxf(fmaf(AC1[j], h1p[j], AC1[32 + j]), 0.f);
#pragma unroll
        for (int j = 0; j < 32; ++j) h2[j] = e_b2[j];
        matvec32(eW2, h1p, h2);
    } else {
#pragma unroll
        for (int j = 0; j < 32; ++j) h2[j] = 0.f;
    }
    stats_reduce(h2, pb);
}

__global__ __launch_bounds__(TPB) void edge3_kernel(
    const float* __restrict__ e, const int* __restrict__ ei,
    const float* __restrict__ Q, const float* __restrict__ e_b1,
    const float* __restrict__ eW1, const float* __restrict__ eps2p,
    const float* __restrict__ AC1,
    const float* __restrict__ eW2, const float* __restrict__ e_b2,
    const float* __restrict__ AC2,
    float* __restrict__ out_e, int E)
{
    int eid = blockIdx.x * TPB + threadIdx.x;
    if (eid >= E) return;
    int s = ei[eid];
    int d = ei[(size_t)E + eid];
    float ev[32]; load_row(e + (size_t)eid * 32, ev);
    float h1p[32];
    load_row(Q + (size_t)s * 32, h1p);
    {
        float qd[32]; load_row(Q + (size_t)d * 32, qd);
#pragma unroll
        for (int j = 0; j < 32; ++j) h1p[j] += qd[j] + e_b1[j];
    }
    float t = 1.0f + eps2p[0];
#pragma unroll
    for (int k = 0; k < 32; ++k) ev[k] *= t;
    matvec32(eW1, ev, h1p);
#pragma unroll
    for (int j = 0; j < 32; ++j) h1p[j] = fmaxf(fmaf(AC1[j], h1p[j], AC1[32 + j]), 0.f);
    float h2[32];
#pragma unroll
    for (int j = 0; j < 32; ++j) h2[j] = e_b2[j];
    matvec32(eW2, h1p, h2);
#pragma unroll
    for (int j = 0; j < 32; ++j) h2[j] = fmaxf(fmaf(AC2[j], h2[j], AC2[32 + j]), 0.f);
    store_row(out_e + (size_t)eid * 32, h2);
}

// ---------- hierarchical stats reduction ----------
// 64 blocks; block b double-sums rows {b+64q+256k} of pb -> pb2[b*64+c]
__global__ __launch_bounds__(TPB) void mid_reduce(
    const float* __restrict__ pb, int nrows, float* __restrict__ pb2)
{
    __shared__ double sh[4][64];
    const int c = threadIdx.x & 63;
    const int q = threadIdx.x >> 6;
    double acc = 0.0;
    for (int r = blockIdx.x + q * 64; r < nrows; r += 256)
        acc += (double)pb[(size_t)r * 64 + c];
    sh[q][c] = acc;
    __syncthreads();
    if (threadIdx.x < 64)
        pb2[(size_t)blockIdx.x * 64 + threadIdx.x] =
            (float)(sh[0][threadIdx.x] + sh[1][threadIdx.x] +
                    sh[2][threadIdx.x] + sh[3][threadIdx.x]);
}

__global__ __launch_bounds__(TPB) void fin_kernel(
    const float* __restrict__ pb, int nblocks, double inv_count,
    const float* __restrict__ g, const float* __restrict__ be, float* __restrict__ AC)
{
    __shared__ double sh[256];
    const int c = threadIdx.x & 63;
    const int q = threadIdx.x >> 6;
    double acc = 0.0;
    for (int b = q; b < nblocks; b += 4) acc += (double)pb[(size_t)b * 64 + c];
    sh[threadIdx.x] = acc;
    __syncthreads();
    if (threadIdx.x < 64) {
        double t = sh[c] + sh[64 + c] + sh[128 + c] + sh[192 + c];
        sh[c] = t;
    }
    __syncthreads();
    if (threadIdx.x < 32) {
        int j = threadIdx.x;
        double mean = sh[j] * inv_count;
        double var  = sh[32 + j] * inv_count - mean * mean;
        float rstd = rsqrtf((float)var + 1e-5f);
        float gv = g[j];
        AC[j]      = gv * rstd;
        AC[32 + j] = be[j] - gv * (float)mean * rstd;
    }
}

// ---------- node path: pull-gather + fused layer1 ----------
__global__ __launch_bounds__(TPB) void gather_node1(
    const float* __restrict__ x, const float* __restrict__ e,
    const int* __restrict__ ei, const float* __restrict__ P,
    const float* __restrict__ Wmsg_lo,
    const int* __restrict__ row_start, const int* __restrict__ count,
    const int* __restrict__ perm,
    const float* __restrict__ eps1p,
    const float* __restrict__ nW1, const float* __restrict__ n_b1,
    float* __restrict__ h_n, float* __restrict__ pb, int n)
{
    int i = blockIdx.x * TPB + threadIdx.x;
    float h[32];
    if (i < n) {
        float acc[32];
#pragma unroll
        for (int j = 0; j < 32; ++j) acc[j] = 0.f;
        int start = row_start[i];
        int deg   = count[i];
        for (int k = 0; k < deg; ++k) {
            int eid = perm[start + k];
            int s   = ei[eid];
            float ev[32]; load_row(e + (size_t)eid * 32, ev);
            float m[32];  load_row(P + (size_t)s * 32, m);   // P has b_msg folded in
            matvec32(Wmsg_lo, ev, m);
#pragma unroll
            for (int j = 0; j < 32; ++j) acc[j] += fmaxf(m[j], 0.f);
        }
        float xv[32]; load_row(x + (size_t)i * 32, xv);
        float t = 1.0f + eps1p[0];
#pragma unroll
        for (int j = 0; j < 32; ++j) acc[j] = fmaf(t, xv[j], acc[j]);
#pragma unroll
        for (int j = 0; j < 32; ++j) h[j] = n_b1[j];
        matvec32(nW1, acc, h);
        store_row(h_n + (size_t)i * 32, h);
    } else {
#pragma unroll
        for (int j = 0; j < 32; ++j) h[j] = 0.f;
    }
    stats_reduce(h, pb);
}

__global__ __launch_bounds__(TPB) void node2_kernel(
    const float* __restrict__ AC1, const float* __restrict__ nW2,
    const float* __restrict__ n_b2, float* __restrict__ h_n,
    float* __restrict__ pb, int n)
{
    int i = blockIdx.x * TPB + threadIdx.x;
    float acc[32];
    if (i < n) {
        float hp[32]; load_row(h_n + (size_t)i * 32, hp);
#pragma unroll
        for (int j = 0; j < 32; ++j) hp[j] = fmaxf(fmaf(AC1[j], hp[j], AC1[32 + j]), 0.f);
#pragma unroll
        for (int j = 0; j < 32; ++j) acc[j] = n_b2[j];
        matvec32(nW2, hp, acc);
        store_row(h_n + (size_t)i * 32, acc);
    } else {
#pragma unroll
        for (int j = 0; j < 32; ++j) acc[j] = 0.f;
    }
    stats_reduce(acc, pb);
}

__global__ __launch_bounds__(TPB) void node3_kernel(
    const float* __restrict__ AC2, const float* __restrict__ h_n,
    float* __restrict__ out_n, int n)
{
    int i = blockIdx.x * TPB + threadIdx.x;
    if (i >= n) return;
    float hp[32]; load_row(h_n + (size_t)i * 32, hp);
    float o[32];
#pragma unroll
    for (int j = 0; j < 32; ++j) o[j] = fmaxf(fmaf(AC2[j], hp[j], AC2[32 + j]), 0.f);
    store_row(out_n + (size_t)i * 32, o);
}

extern "C" void kernel_launch(void* const* d_in, const int* in_sizes, int n_in,
                              void* d_out, int out_size, void* d_ws, size_t ws_size,
                              hipStream_t stream) {
    const float* x        = (const float*)d_in[0];
    const float* e        = (const float*)d_in[1];
    const int*   ei       = (const int*)d_in[2];
    const float* W_msg    = (const float*)d_in[3];
    const float* b_msg    = (const float*)d_in[4];
    const float* n_W1     = (const float*)d_in[5];
    const float* n_b1     = (const float*)d_in[6];
    const float* n_g1     = (const float*)d_in[7];
    const float* n_be1    = (const float*)d_in[8];
    const float* n_W2     = (const float*)d_in[9];
    const float* n_b2     = (const float*)d_in[10];
    const float* n_g2     = (const float*)d_in[11];
    const float* n_be2    = (const float*)d_in[12];
    const float* e_W1     = (const float*)d_in[13];
    const float* e_b1     = (const float*)d_in[14];
    const float* e_g1     = (const float*)d_in[15];
    const float* e_be1    = (const float*)d_in[16];
    const float* e_W2     = (const float*)d_in[17];
    const float* e_b2     = (const float*)d_in[18];
    const float* e_g2     = (const float*)d_in[19];
    const float* e_be2    = (const float*)d_in[20];
    const float* eps1     = (const float*)d_in[21];
    const float* eps2     = (const float*)d_in[22];

    const int N = in_sizes[0] / 32;   // 50000
    const int E = in_sizes[1] / 32;   // 1600000
    const int NB = (N + TPB - 1) / TPB;   // 196
    const int EB = (E + TPB - 1) / TPB;   // 6250

    char* ws = (char*)d_ws;
    const size_t nb = (size_t)N * 32 * sizeof(float);       // 6.4 MB
    float* P         = (float*)(ws);
    float* Q         = (float*)(ws + nb);
    float* h_n       = Q;                                    // Q dead after edge3
    float* pb        = (float*)(ws + 2 * nb);
    size_t pb_bytes  = (size_t)EB * 64 * sizeof(float);      // 1.6 MB
    int*   perm      = (int*)(ws + 2 * nb + pb_bytes);
    int*   count     = (int*)(ws + 2 * nb + pb_bytes + (size_t)E * sizeof(int));
    int*   row_start = count + N;
    int*   woff      = row_start + N;
    int*   tops      = woff + N;                             // NB ints
    float* AC        = (float*)(tops + ((NB + 255) & ~255)); // aligned past tops
    float* pb2       = AC + 256;                             // 64*64 floats
    // AC layout: [0:64) e-L1, [64:128) e-L2, [128:192) n-L1, [192:256) n-L2

    float* out_n = (float*)d_out;
    float* out_e = (float*)d_out + (size_t)N * 32;

    hipMemsetAsync(count, 0, (size_t)N * sizeof(int), stream);

    precompute_pq<<<NB, TPB, 0, stream>>>(x, W_msg, b_msg, e_W1, P, Q, N);

    // CSR build (int atomics only)
    hist_kernel   <<<EB, TPB, 0, stream>>>(ei, count, E);
    scanA_kernel  <<<NB, TPB, 0, stream>>>(count, row_start, tops, N);
    scanB_kernel  <<<1,  TPB, 0, stream>>>(tops, NB);
    scanC_kernel  <<<NB, TPB, 0, stream>>>(row_start, tops, woff, N);
    scatter_kernel<<<EB, TPB, 0, stream>>>(ei, woff, perm, E);

    // edge pipeline
    edge1_stats<<<EB, TPB, 0, stream>>>(e, ei, Q, e_b1, e_W1, eps2, pb, E);
    mid_reduce<<<64, TPB, 0, stream>>>(pb, EB, pb2);
    fin_kernel<<<1, TPB, 0, stream>>>(pb2, 64, 1.0 / (double)E, e_g1, e_be1, AC + 0);
    edge2_kernel<<<EB, TPB, 0, stream>>>(e, ei, Q, e_b1, e_W1, eps2, AC + 0,
                                         e_W2, e_b2, pb, E);
    mid_reduce<<<64, TPB, 0, stream>>>(pb, EB, pb2);
    fin_kernel<<<1, TPB, 0, stream>>>(pb2, 64, 1.0 / (double)E, e_g2, e_be2, AC + 64);
    edge3_kernel<<<EB, TPB, 0, stream>>>(e, ei, Q, e_b1, e_W1, eps2, AC + 0,
                                         e_W2, e_b2, AC + 64, out_e, E);

    // node pipeline (gather must follow edge3: h_n aliases Q)
    gather_node1<<<NB, TPB, 0, stream>>>(x, e, ei, P, W_msg + 32 * 32,
                                         row_start, count, perm, eps1,
                                         n_W1, n_b1, h_n, pb, N);
    mid_reduce<<<64, TPB, 0, stream>>>(pb, NB, pb2);
    fin_kernel<<<1, TPB, 0, stream>>>(pb2, 64, 1.0 / (double)N, n_g1, n_be1, AC + 128);
    node2_kernel<<<NB, TPB, 0, stream>>>(AC + 128, n_W2, n_b2, h_n, pb, N);
    mid_reduce<<<64, TPB, 0, stream>>>(pb, NB, pb2);
    fin_kernel<<<1, TPB, 0, stream>>>(pb2, 64, 1.0 / (double)N, n_g2, n_be2, AC + 192);
    node3_kernel<<<NB, TPB, 0, stream>>>(AC + 192, h_n, out_n, N);
}